// Round 16
// baseline (1051.513 us; speedup 1.0000x reference)
//
#include <hip/hip_runtime.h>

#define NN 262144
#define HH 512
#define CC 32
#define MOMF 0.99f

// ws layout (float offsets). Total 344576 floats = 1.35 MB (< proven 1.84 MB).
#define WS_SUMS   0         // 8 x 16384 partial sums
#define WS_COUNTS 131072    // 8 x 32 partial counts
#define WS_UPD    131328
#define WS_KBUF   147712
#define WS_VBUF   164096
#define WS_SB     180480
#define WS_MT     180736    // ushort[16][256][32] (bf16, kk-slice-major)
#define WS_PT     246272    // ushort[8][512][32]  (bf16, h-slice-major)
#define WS_ASSIGN 279040    // uchar[262144] = 65536 floats

typedef __attribute__((ext_vector_type(8))) short s8v;
typedef __attribute__((ext_vector_type(4))) float f4v;
typedef __attribute__((ext_vector_type(4))) unsigned int u4v;

static __device__ __forceinline__ unsigned short f2bf(float f) {
  unsigned int u = __float_as_uint(f);
  u += 0x7FFFu + ((u >> 16) & 1u);   // round-to-nearest-even
  return (unsigned short)(u >> 16);
}
static __device__ __forceinline__ unsigned int pk2bf(float a, float b) {
  return (unsigned int)f2bf(a) | ((unsigned int)f2bf(b) << 16);
}
#define EL4(v, k) ((k) == 0 ? (v).x : (k) == 1 ? (v).y : (k) == 2 ? (v).z : (v).w)

// ---------------------------------------------------------------------------
// Kernel 1a: assignment only — R9-R15 exact (174 µs, ~3.1 TB/s).
// ---------------------------------------------------------------------------
__global__ __launch_bounds__(256) void k_asn(const float* __restrict__ x,
                                             const float* __restrict__ cent,
                                             unsigned char* __restrict__ sag) {
  __shared__ __align__(16) unsigned char smem[34432];
  unsigned short* clbf = (unsigned short*)smem;        // [32][520] bf16
  float* cnS = (float*)(smem + 33280);                 // 32 floats
  float* scratch = (float*)(smem + 33408);             // 256 floats

  const int tid = threadIdx.x;
  const int w = tid >> 6, l = tid & 63;
  const int l16 = l & 15, g = l >> 4;

  // stage cent -> bf16 LDS [32][520]
  for (int i = tid * 8; i < CC * HH; i += 256 * 8) {
    float4 a = *(const float4*)&cent[i];
    float4 b = *(const float4*)&cent[i + 4];
    const int row = i >> 9, col = i & 511;
    u4v p;
    p[0] = pk2bf(a.x, a.y); p[1] = pk2bf(a.z, a.w);
    p[2] = pk2bf(b.x, b.y); p[3] = pk2bf(b.z, b.w);
    *(u4v*)((unsigned char*)clbf + row * 1040 + col * 2) = p;
  }
  // ||c||^2 partials: c = tid>>3, kk = tid&7
  {
    const int c = tid >> 3, kk = tid & 7;
    float p = 0.f;
    for (int m = 0; m < 64; ++m) { float v = cent[c * HH + kk + 8 * m]; p += v * v; }
    scratch[tid] = p;
  }
  __syncthreads();
  if (tid < CC) {
    float s = 0.f;
#pragma unroll
    for (int m = 0; m < 8; ++m) s += scratch[tid * 8 + m];
    cnS[tid] = s;
  }
  __syncthreads();

  float cnr[8];
#pragma unroll
  for (int tc = 0; tc < 2; ++tc)
#pragma unroll
    for (int r = 0; r < 4; ++r) cnr[tc * 4 + r] = cnS[tc * 16 + 4 * g + r];

  for (int pass = 0; pass < 2; ++pass) {
    const int nodeloc = pass * 64 + w * 16 + l16;
    const float* xr = x + ((size_t)blockIdx.x * 128 + nodeloc) * HH;
    f4v acc[2];
    acc[0] = (f4v){0.f, 0.f, 0.f, 0.f};
    acc[1] = (f4v){0.f, 0.f, 0.f, 0.f};
    float4 pa[2][4], pb[2][4];
#pragma unroll
    for (int k = 0; k < 4; ++k) {
      pa[0][k] = *(const float4*)&xr[k * 32 + g * 8];
      pb[0][k] = *(const float4*)&xr[k * 32 + g * 8 + 4];
    }
#pragma unroll
    for (int c4 = 0; c4 < 4; ++c4) {
      const int cur = c4 & 1, nxt = cur ^ 1;
      if (c4 < 3) {
#pragma unroll
        for (int k = 0; k < 4; ++k) {
          const int kk = (c4 + 1) * 4 + k;
          pa[nxt][k] = *(const float4*)&xr[kk * 32 + g * 8];
          pb[nxt][k] = *(const float4*)&xr[kk * 32 + g * 8 + 4];
        }
      }
#pragma unroll
      for (int k = 0; k < 4; ++k) {
        const int kk = c4 * 4 + k;
        float4 xa = pa[cur][k], xb = pb[cur][k];
        s8v bfrag;
        bfrag[0] = (short)f2bf(xa.x); bfrag[1] = (short)f2bf(xa.y);
        bfrag[2] = (short)f2bf(xa.z); bfrag[3] = (short)f2bf(xa.w);
        bfrag[4] = (short)f2bf(xb.x); bfrag[5] = (short)f2bf(xb.y);
        bfrag[6] = (short)f2bf(xb.z); bfrag[7] = (short)f2bf(xb.w);
#pragma unroll
        for (int tc = 0; tc < 2; ++tc) {
          s8v afrag = *(const s8v*)((unsigned char*)clbf +
                                    (tc * 16 + l16) * 1040 + kk * 64 + g * 16);
          acc[tc] = __builtin_amdgcn_mfma_f32_16x16x32_bf16(afrag, bfrag, acc[tc], 0, 0, 0);
        }
      }
    }
    float bv = 3.4e38f; int bi = 0;
#pragma unroll
    for (int tc = 0; tc < 2; ++tc)
#pragma unroll
      for (int r = 0; r < 4; ++r) {
        const int c = tc * 16 + 4 * g + r;
        const float v = cnr[tc * 4 + r] - 2.f * acc[tc][r];
        if (v < bv) { bv = v; bi = c; }
      }
#pragma unroll
    for (int m = 16; m <= 32; m <<= 1) {
      const float ov = __shfl_xor(bv, m);
      const int oi = __shfl_xor(bi, m);
      if (ov < bv || (ov == bv && oi < bi)) { bv = ov; bi = oi; }
    }
    if (l < 16) sag[(size_t)blockIdx.x * 128 + nodeloc] = (unsigned char)bi;
  }
}

// ---------------------------------------------------------------------------
// Kernel 1b: segment-sum as onehot-GEMM — R11-R15 exact (~150 µs).
// ---------------------------------------------------------------------------
__global__ __launch_bounds__(256) void k_sum(const float* __restrict__ x,
                                             const unsigned char* __restrict__ sag,
                                             float* __restrict__ gsums,
                                             float* __restrict__ gcounts) {
  __shared__ __align__(16) unsigned char xt[32768];   // [col 512][node 32] bf16
  const int tid = threadIdx.x;
  const int w = tid >> 6, l = tid & 63;
  const int l16 = l & 15, g = l >> 4;
  const int q = tid & 7, cc = tid >> 3;
  const size_t node0 = (size_t)blockIdx.x * 512;
  const unsigned char* sab = sag + node0;

  f4v acc[8][2];
#pragma unroll
  for (int ct = 0; ct < 8; ++ct) {
    acc[ct][0] = (f4v){0.f, 0.f, 0.f, 0.f};
    acc[ct][1] = (f4v){0.f, 0.f, 0.f, 0.f};
  }

  for (int step = 0; step < 16; ++step) {
    float4 r[4][4];
    const float* xs = x + (node0 + step * 32 + q * 4) * HH + cc * 16;
#pragma unroll
    for (int nn = 0; nn < 4; ++nn)
#pragma unroll
      for (int f = 0; f < 4; ++f)
        r[nn][f] = *(const float4*)&xs[nn * HH + f * 4];
    const uint2 awv = *(const uint2*)(sab + step * 32 + 8 * g);
    __syncthreads();
#pragma unroll
    for (int j = 0; j < 16; ++j) {
      uint2 p;
      p.x = pk2bf(EL4(r[0][j >> 2], j & 3), EL4(r[1][j >> 2], j & 3));
      p.y = pk2bf(EL4(r[2][j >> 2], j & 3), EL4(r[3][j >> 2], j & 3));
      *(uint2*)(xt + (cc * 16 + j) * 64 + q * 8) = p;
    }
    __syncthreads();
    s8v oh0, oh1;
#pragma unroll
    for (int j = 0; j < 8; ++j) {
      const unsigned a = ((j < 4 ? awv.x >> (8 * j) : awv.y >> (8 * (j - 4)))) & 255u;
      oh0[j] = (a == (unsigned)l16) ? (short)0x3F80 : (short)0;
      oh1[j] = (a == (unsigned)(16 + l16)) ? (short)0x3F80 : (short)0;
    }
#pragma unroll
    for (int ct = 0; ct < 8; ++ct) {
      s8v af = *(const s8v*)(xt + (w * 128 + ct * 16 + l16) * 64 + g * 16);
      acc[ct][0] = __builtin_amdgcn_mfma_f32_16x16x32_bf16(af, oh0, acc[ct][0], 0, 0, 0);
      acc[ct][1] = __builtin_amdgcn_mfma_f32_16x16x32_bf16(af, oh1, acc[ct][1], 0, 0, 0);
    }
  }

  const int pb = blockIdx.x & 7;
#pragma unroll
  for (int ct = 0; ct < 8; ++ct)
#pragma unroll
    for (int tc = 0; tc < 2; ++tc) {
      const int c = tc * 16 + l16;
      const int xcol = w * 128 + ct * 16 + 4 * g;
#pragma unroll
      for (int r = 0; r < 4; ++r)
        atomicAdd(&gsums[pb * 16384 + c * HH + xcol + r], acc[ct][tc][r]);
    }

  if (w == 0 && l < CC) {
    int cnt = 0;
    for (int i = 0; i < 512; i += 4) {
      const unsigned wd = *(const unsigned*)(sab + i);
      cnt += (int)((wd & 255u) == (unsigned)l) + (int)(((wd >> 8) & 255u) == (unsigned)l) +
             (int)(((wd >> 16) & 255u) == (unsigned)l) + (int)(((wd >> 24) & 255u) == (unsigned)l);
    }
    atomicAdd(&gcounts[pb * 32 + l], (float)cnt);
  }
}

// ---------------------------------------------------------------------------
// Kernel 3: reduce 8 partials + EMA centroid update — R8+ exact
// ---------------------------------------------------------------------------
__global__ void k_upd(const float* __restrict__ cent, const float* __restrict__ sums,
                      const float* __restrict__ counts, float* __restrict__ upd) {
  const int i = blockIdx.x * 256 + threadIdx.x;   // 16384
  const int c = i >> 9;
  float s = 0.f, cnt = 0.f;
#pragma unroll
  for (int b = 0; b < 8; ++b) { s += sums[b * 16384 + i]; cnt += counts[b * 32 + c]; }
  const float mean = s / fmaxf(cnt, 1.f);
  upd[i] = (cnt > 0.f) ? (MOMF * cent[i] + (1.f - MOMF) * mean) : cent[i];
}

// ---------------------------------------------------------------------------
// Kernel 4: k = upd@Wk + bk ; v = upd@Wv + bv   (32x512 each) — R2 exact
// ---------------------------------------------------------------------------
__global__ void k_kv(const float* __restrict__ upd,
                     const float* __restrict__ Wk, const float* __restrict__ bk,
                     const float* __restrict__ Wv, const float* __restrict__ bv,
                     float* __restrict__ kbuf, float* __restrict__ vbuf) {
  const int o = blockIdx.x * 256 + threadIdx.x;   // 0..32767
  const int sel = o >> 14;
  const int idx = o & 16383;
  const int c = idx >> 9, j = idx & 511;
  const float* W = sel ? Wv : Wk;
  const float* b = sel ? bv : bk;
  const float* u = upd + c * HH;
  float s = b[j];
  for (int i = 0; i < HH; ++i) s += u[i] * W[i * HH + j];
  (sel ? vbuf : kbuf)[idx] = s;
}

// ---------------------------------------------------------------------------
// Kernel 5: Mt/Pt slice-major — R12-R15 exact.
// ---------------------------------------------------------------------------
__global__ void k_msp(const float* __restrict__ Wq, const float* __restrict__ bq,
                      const float* __restrict__ kbuf, const float* __restrict__ vbuf,
                      const float* __restrict__ Wo, const float* __restrict__ bo,
                      unsigned short* __restrict__ Mt, float* __restrict__ sb,
                      unsigned short* __restrict__ Pt) {
  const int b = blockIdx.x, t = threadIdx.x;
  const float scale = 0.125f;   // 1/sqrt(64)
  if (b < 512) {
    const int o = b * 256 + t;          // hc*512 + i
    const int hc = o >> 9, i = o & 511;
    const int h = hc >> 5, c = hc & 31;
    const float* wq = Wq + i * HH + h * 64;
    const float* kr = kbuf + c * HH + h * 64;
    float s = 0.f;
#pragma unroll
    for (int d = 0; d < 64; ++d) s += wq[d] * kr[d];
    Mt[(i >> 5) * 8192 + hc * 32 + (i & 31)] = f2bf(s * scale);
  } else if (b < 1024) {
    const int o = b - 512;              // output col (0..511)
    const int hc = t;                   // 0..255
    const int h = hc >> 5, c = hc & 31;
    const float* vr = vbuf + c * HH + h * 64;
    const float* wo = Wo + h * 64 * HH + o;
    float s = 0.f;
#pragma unroll
    for (int d = 0; d < 64; ++d) s += vr[d] * wo[d * HH];
    Pt[h * 16384 + o * 32 + (hc & 31)] = f2bf(s + bo[o] * scale);
  } else if (t < 256) {
    const int h = t >> 5, c = t & 31;
    const float* kr = kbuf + c * HH + h * 64;
    const float* bqp = bq + h * 64;
    float s = 0.f;
#pragma unroll
    for (int d = 0; d < 64; ++d) s += bqp[d] * kr[d];
    sb[t] = s * scale;
  }
}

// ---------------------------------------------------------------------------
// Kernel 6 (main, MFMA): NO LDS STAGING. A-frags loaded directly from
// slice-major Mt2/Pt2 in global (L2/L1-hot): for fixed tc, lanes (l16,g)
// read byte tc*1024 + l16*64 + g*16 — a contiguous 1KB wave-segment (ideal
// coalescing). No barriers in the main loops; waves run free with 16
// outstanding loads each. Math/accumulation order bit-identical to R12-R15.
// LDS = 33280B store window only.
// ---------------------------------------------------------------------------
__global__ __launch_bounds__(256, 2) void k_main(
    const float* __restrict__ x, const unsigned short* __restrict__ Mt,
    const float* __restrict__ sb, const unsigned short* __restrict__ Pt,
    const float* __restrict__ lnw, const float* __restrict__ lnb,
    float* __restrict__ y) {
  __shared__ __align__(16) float yb[16 * 520];   // 33280 B store window
  const unsigned char* Mtb = (const unsigned char*)Mt;
  const unsigned char* Ptb = (const unsigned char*)Pt;
  const int tid = threadIdx.x;
  const int w = tid >> 6, l = tid & 63;
  const int l16 = l & 15, g = l >> 4;            // lane column / k-group
  const size_t n0 = (size_t)blockIdx.x * 64;
  const size_t xrow = n0 + w * 16 + l16;
  const float* xr = x + xrow * HH;
  const int laneoff = l16 * 64 + g * 16;         // within-slice coalesced offset

  // ---- phase 1: S^T[score_col=16tc+4g+r][xrow] ----
  f4v acc1[16];
#pragma unroll
  for (int tc = 0; tc < 16; ++tc)
    acc1[tc] = *(const f4v*)&sb[tc * 16 + 4 * g];

#pragma unroll
  for (int kk = 0; kk < 16; ++kk) {
    float4 xa = *(const float4*)&xr[kk * 32 + g * 8];
    float4 xb = *(const float4*)&xr[kk * 32 + g * 8 + 4];
    s8v bfrag;
    bfrag[0] = (short)f2bf(xa.x); bfrag[1] = (short)f2bf(xa.y);
    bfrag[2] = (short)f2bf(xa.z); bfrag[3] = (short)f2bf(xa.w);
    bfrag[4] = (short)f2bf(xb.x); bfrag[5] = (short)f2bf(xb.y);
    bfrag[6] = (short)f2bf(xb.z); bfrag[7] = (short)f2bf(xb.w);
    const unsigned char* base = Mtb + kk * 16384 + laneoff;
#pragma unroll
    for (int tc = 0; tc < 16; ++tc) {
      s8v afrag = *(const s8v*)(base + tc * 1024);
      acc1[tc] = __builtin_amdgcn_mfma_f32_16x16x32_bf16(afrag, bfrag, acc1[tc], 0, 0, 0);
    }
  }

  // ---- softmax per head h (cols 32h..32h+31): 8 in-lane + xor16/xor32 ----
  unsigned int apk[16][2];
#pragma unroll
  for (int h = 0; h < 8; ++h) {
    f4v s0 = acc1[2 * h], s1 = acc1[2 * h + 1];
    float m = fmaxf(fmaxf(fmaxf(s0[0], s0[1]), fmaxf(s0[2], s0[3])),
                    fmaxf(fmaxf(s1[0], s1[1]), fmaxf(s1[2], s1[3])));
    m = fmaxf(m, __shfl_xor(m, 16));
    m = fmaxf(m, __shfl_xor(m, 32));
    float e0 = __expf(s0[0] - m), e1 = __expf(s0[1] - m);
    float e2 = __expf(s0[2] - m), e3 = __expf(s0[3] - m);
    float e4 = __expf(s1[0] - m), e5 = __expf(s1[1] - m);
    float e6 = __expf(s1[2] - m), e7 = __expf(s1[3] - m);
    float sum = ((e0 + e1) + (e2 + e3)) + ((e4 + e5) + (e6 + e7));
    sum += __shfl_xor(sum, 16);
    sum += __shfl_xor(sum, 32);
    const float inv = 1.f / sum;
    apk[2 * h][0] = pk2bf(e0 * inv, e1 * inv);
    apk[2 * h][1] = pk2bf(e2 * inv, e3 * inv);
    apk[2 * h + 1][0] = pk2bf(e4 * inv, e5 * inv);
    apk[2 * h + 1][1] = pk2bf(e6 * inv, e7 * inv);
  }

  // ---- phase 2: 16 half-slice steps (h = s>>1, half = s&1), direct loads ----
  f4v acc2[32];
#pragma unroll
  for (int to = 0; to < 32; ++to) acc2[to] = (f4v){0.f, 0.f, 0.f, 0.f};

#pragma unroll
  for (int s = 0; s < 16; ++s) {
    const int h = s >> 1, half = s & 1;
    unsigned int dw[4];
#pragma unroll
    for (int d = 0; d < 4; ++d) {
      const int gsrc = 2 * (g & 1) + (d >> 1);
      const int src = l16 + 16 * gsrc;
      unsigned int t0 = (unsigned int)__shfl((int)apk[2 * h][d & 1], src, 64);
      unsigned int t1 = (unsigned int)__shfl((int)apk[2 * h + 1][d & 1], src, 64);
      dw[d] = (g < 2) ? t0 : t1;
    }
    u4v bu; bu[0] = dw[0]; bu[1] = dw[1]; bu[2] = dw[2]; bu[3] = dw[3];
    s8v bfrag = __builtin_bit_cast(s8v, bu);
    const unsigned char* base = Ptb + s * 16384 + laneoff;
#pragma unroll
    for (int tl = 0; tl < 16; ++tl) {
      s8v afrag = *(const s8v*)(base + tl * 1024);
      acc2[half * 16 + tl] =
          __builtin_amdgcn_mfma_f32_16x16x32_bf16(afrag, bfrag, acc2[half * 16 + tl], 0, 0, 0);
    }
  }

  // ---- epilogue: +residual (bo folded into Pt), LN in registers ----
  float s1 = 0.f, s2 = 0.f;
#pragma unroll
  for (int to = 0; to < 32; ++to) {
    float4 xv = *(const float4*)&xr[to * 16 + 4 * g];
    acc2[to][0] += xv.x; acc2[to][1] += xv.y;
    acc2[to][2] += xv.z; acc2[to][3] += xv.w;
    s1 += (acc2[to][0] + acc2[to][1]) + (acc2[to][2] + acc2[to][3]);
    s2 += (acc2[to][0] * acc2[to][0] + acc2[to][1] * acc2[to][1]) +
          (acc2[to][2] * acc2[to][2] + acc2[to][3] * acc2[to][3]);
  }
  s1 += __shfl_xor(s1, 16); s2 += __shfl_xor(s2, 16);
  s1 += __shfl_xor(s1, 32); s2 += __shfl_xor(s2, 32);
  const float mean = s1 * (1.f / 512.f);
  const float var = s2 * (1.f / 512.f) - mean * mean;
  const float rstd = rsqrtf(var + 1e-5f);
#pragma unroll
  for (int to = 0; to < 32; ++to) {
    float4 wv = *(const float4*)&lnw[to * 16 + 4 * g];
    float4 bv = *(const float4*)&lnb[to * 16 + 4 * g];
    acc2[to][0] = (acc2[to][0] - mean) * rstd * wv.x + bv.x;
    acc2[to][1] = (acc2[to][1] - mean) * rstd * wv.y + bv.y;
    acc2[to][2] = (acc2[to][2] - mean) * rstd * wv.z + bv.z;
    acc2[to][3] = (acc2[to][3] - mean) * rstd * wv.w + bv.w;
  }

  // ---- store via LDS windows (R12 exact) ----
  const int prow = tid >> 7;               // 0..1
  const int pc = (tid & 127) * 4;          // float col within row
  for (int j = 0; j < 4; ++j) {
    __syncthreads();                       // window free
    if (w == j) {
#pragma unroll
      for (int to = 0; to < 32; ++to)
        *(f4v*)&yb[l16 * 520 + to * 16 + 4 * g] = acc2[to];
    }
    __syncthreads();                       // publish
#pragma unroll
    for (int p = 0; p < 8; ++p)
      *(float4*)&y[(n0 + j * 16 + p * 2 + prow) * HH + pc] =
          *(const float4*)&yb[(p * 2 + prow) * 520 + pc];
  }
}

// ---------------------------------------------------------------------------
extern "C" void kernel_launch(void* const* d_in, const int* in_sizes, int n_in,
                              void* d_out, int out_size, void* d_ws, size_t ws_size,
                              hipStream_t stream) {
  const float* x    = (const float*)d_in[0];
  const float* cent = (const float*)d_in[1];
  const float* Wq   = (const float*)d_in[2];
  const float* bq   = (const float*)d_in[3];
  const float* Wk   = (const float*)d_in[4];
  const float* bk   = (const float*)d_in[5];
  const float* Wv   = (const float*)d_in[6];
  const float* bv   = (const float*)d_in[7];
  const float* Wo   = (const float*)d_in[8];
  const float* bo   = (const float*)d_in[9];
  const float* lnw  = (const float*)d_in[10];
  const float* lnb  = (const float*)d_in[11];
  float* ws = (float*)d_ws;
  float* y  = (float*)d_out;

  hipMemsetAsync(ws, 0, (8 * 16384 + 8 * 32) * sizeof(float), stream);
  k_asn<<<2048, 256, 0, stream>>>(x, cent, (unsigned char*)(ws + WS_ASSIGN));
  k_sum<<<512, 256, 0, stream>>>(x, (const unsigned char*)(ws + WS_ASSIGN),
                                 ws + WS_SUMS, ws + WS_COUNTS);
  k_upd<<<64, 256, 0, stream>>>(cent, ws + WS_SUMS, ws + WS_COUNTS, ws + WS_UPD);
  k_kv<<<128, 256, 0, stream>>>(ws + WS_UPD, Wk, bk, Wv, bv,
                                ws + WS_KBUF, ws + WS_VBUF);
  k_msp<<<1025, 256, 0, stream>>>(Wq, bq, ws + WS_KBUF, ws + WS_VBUF, Wo, bo,
                                  (unsigned short*)(ws + WS_MT), ws + WS_SB,
                                  (unsigned short*)(ws + WS_PT));
  k_main<<<4096, 256, 0, stream>>>(x, (const unsigned short*)(ws + WS_MT),
                                   ws + WS_SB, (const unsigned short*)(ws + WS_PT),
                                   lnw, lnb, y);
}

// Round 17
// 810.126 us; speedup vs baseline: 1.2980x; 1.2980x over previous
//
#include <hip/hip_runtime.h>

#define NN 262144
#define HH 512
#define CC 32
#define MOMF 0.99f

// ws layout (float offsets). Total 344576 floats = 1.35 MB (< proven 1.84 MB).
#define WS_SUMS   0         // 8 x 16384 partial sums
#define WS_COUNTS 131072    // 8 x 32 partial counts
#define WS_UPD    131328
#define WS_KBUF   147712
#define WS_VBUF   164096
#define WS_SB     180480
#define WS_MT     180736    // ushort[16][256][32] (bf16, kk-slice-major)
#define WS_PT     246272    // ushort[8][512][32]  (bf16, h-slice-major)

typedef __attribute__((ext_vector_type(8))) short s8v;
typedef __attribute__((ext_vector_type(4))) float f4v;
typedef __attribute__((ext_vector_type(4))) unsigned int u4v;

static __device__ __forceinline__ unsigned short f2bf(float f) {
  unsigned int u = __float_as_uint(f);
  u += 0x7FFFu + ((u >> 16) & 1u);   // round-to-nearest-even
  return (unsigned short)(u >> 16);
}
static __device__ __forceinline__ unsigned int pk2bf(float a, float b) {
  return (unsigned int)f2bf(a) | ((unsigned int)f2bf(b) << 16);
}
#define EL4(v, k) ((k) == 0 ? (v).x : (k) == 1 ? (v).y : (k) == 2 ? (v).z : (v).w)

// ---------------------------------------------------------------------------
// Kernel 1 (fused k-means): 512 blocks x 256 thr, 512 nodes/block.
// Per 64-node chunk: {assignment pass (R9-proven body) -> barrier ->
// 2 onehot-GEMM steps (R11-proven body, sa from LDS)}. The sum-phase x
// re-read trails the assignment read by <=128KB -> L1/L2 hit; HBM reads x once.
// LDS: clbf 33280 | cn 128 | sa 512 | xt 32768 (scratch aliases xt at setup).
// Accumulation order identical to split kernels -> bit-identical results.
// ---------------------------------------------------------------------------
__global__ __launch_bounds__(256) void k_km2(const float* __restrict__ x,
                                             const float* __restrict__ cent,
                                             float* __restrict__ gsums,
                                             float* __restrict__ gcounts) {
  __shared__ __align__(16) unsigned char smem[66688];
  unsigned short* clbf = (unsigned short*)smem;        // [32][520] bf16
  float* cnS = (float*)(smem + 33280);                 // 32 floats
  unsigned char* saL = smem + 33408;                   // 512 assignments
  unsigned char* xt = smem + 33920;                    // [col 512][node 32] bf16
  float* scratch = (float*)(smem + 33920);             // setup only (aliases xt)

  const int tid = threadIdx.x;
  const int w = tid >> 6, l = tid & 63;
  const int l16 = l & 15, g = l >> 4;

  // ---- setup: stage cent bf16 + ||c||^2 (R9 k_asn verbatim) ----
  for (int i = tid * 8; i < CC * HH; i += 256 * 8) {
    float4 a = *(const float4*)&cent[i];
    float4 b = *(const float4*)&cent[i + 4];
    const int row = i >> 9, col = i & 511;
    u4v p;
    p[0] = pk2bf(a.x, a.y); p[1] = pk2bf(a.z, a.w);
    p[2] = pk2bf(b.x, b.y); p[3] = pk2bf(b.z, b.w);
    *(u4v*)((unsigned char*)clbf + row * 1040 + col * 2) = p;
  }
  {
    const int c = tid >> 3, kk = tid & 7;
    float p = 0.f;
    for (int m = 0; m < 64; ++m) { float v = cent[c * HH + kk + 8 * m]; p += v * v; }
    scratch[tid] = p;
  }
  __syncthreads();
  if (tid < CC) {
    float s = 0.f;
#pragma unroll
    for (int m = 0; m < 8; ++m) s += scratch[tid * 8 + m];
    cnS[tid] = s;
  }
  __syncthreads();

  float cnr[8];
#pragma unroll
  for (int tc = 0; tc < 2; ++tc)
#pragma unroll
    for (int r = 0; r < 4; ++r) cnr[tc * 4 + r] = cnS[tc * 16 + 4 * g + r];

  const size_t node0 = (size_t)blockIdx.x * 512;
  const int q = tid & 7, cc = tid >> 3;   // sum-step staging map

  f4v acc[8][2];
#pragma unroll
  for (int ct = 0; ct < 8; ++ct) {
    acc[ct][0] = (f4v){0.f, 0.f, 0.f, 0.f};
    acc[ct][1] = (f4v){0.f, 0.f, 0.f, 0.f};
  }

  for (int chunk = 0; chunk < 8; ++chunk) {
    // ---- assignment pass for nodes [chunk*64, chunk*64+64) — R9 body ----
    {
      const int nodeloc = chunk * 64 + w * 16 + l16;
      const float* xr = x + (node0 + nodeloc) * HH;
      f4v acA[2];
      acA[0] = (f4v){0.f, 0.f, 0.f, 0.f};
      acA[1] = (f4v){0.f, 0.f, 0.f, 0.f};
      float4 pa[2][4], pb[2][4];
#pragma unroll
      for (int k = 0; k < 4; ++k) {
        pa[0][k] = *(const float4*)&xr[k * 32 + g * 8];
        pb[0][k] = *(const float4*)&xr[k * 32 + g * 8 + 4];
      }
#pragma unroll
      for (int c4 = 0; c4 < 4; ++c4) {
        const int cur = c4 & 1, nxt = cur ^ 1;
        if (c4 < 3) {
#pragma unroll
          for (int k = 0; k < 4; ++k) {
            const int kk = (c4 + 1) * 4 + k;
            pa[nxt][k] = *(const float4*)&xr[kk * 32 + g * 8];
            pb[nxt][k] = *(const float4*)&xr[kk * 32 + g * 8 + 4];
          }
        }
#pragma unroll
        for (int k = 0; k < 4; ++k) {
          const int kk = c4 * 4 + k;
          float4 xa = pa[cur][k], xb = pb[cur][k];
          s8v bfrag;
          bfrag[0] = (short)f2bf(xa.x); bfrag[1] = (short)f2bf(xa.y);
          bfrag[2] = (short)f2bf(xa.z); bfrag[3] = (short)f2bf(xa.w);
          bfrag[4] = (short)f2bf(xb.x); bfrag[5] = (short)f2bf(xb.y);
          bfrag[6] = (short)f2bf(xb.z); bfrag[7] = (short)f2bf(xb.w);
#pragma unroll
          for (int tc = 0; tc < 2; ++tc) {
            s8v afrag = *(const s8v*)((unsigned char*)clbf +
                                      (tc * 16 + l16) * 1040 + kk * 64 + g * 16);
            acA[tc] = __builtin_amdgcn_mfma_f32_16x16x32_bf16(afrag, bfrag, acA[tc], 0, 0, 0);
          }
        }
      }
      float bv = 3.4e38f; int bi = 0;
#pragma unroll
      for (int tc = 0; tc < 2; ++tc)
#pragma unroll
        for (int r = 0; r < 4; ++r) {
          const int c = tc * 16 + 4 * g + r;
          const float v = cnr[tc * 4 + r] - 2.f * acA[tc][r];
          if (v < bv) { bv = v; bi = c; }
        }
#pragma unroll
      for (int m = 16; m <= 32; m <<= 1) {
        const float ov = __shfl_xor(bv, m);
        const int oi = __shfl_xor(bi, m);
        if (ov < bv || (ov == bv && oi < bi)) { bv = ov; bi = oi; }
      }
      if (l < 16) saL[nodeloc] = (unsigned char)bi;
    }
    __syncthreads();                       // publish sa for this chunk

    // ---- two onehot-GEMM steps for this chunk — R11 body, sa from LDS ----
#pragma unroll
    for (int sub = 0; sub < 2; ++sub) {
      const int step = chunk * 2 + sub;
      float4 r[4][4];
      const float* xs = x + (node0 + step * 32 + q * 4) * HH + cc * 16;
#pragma unroll
      for (int nn = 0; nn < 4; ++nn)
#pragma unroll
        for (int f = 0; f < 4; ++f)
          r[nn][f] = *(const float4*)&xs[nn * HH + f * 4];
      const uint2 awv = *(const uint2*)(saL + step * 32 + 8 * g);
      __syncthreads();                     // prev xt readers done
#pragma unroll
      for (int j = 0; j < 16; ++j) {
        uint2 p;
        p.x = pk2bf(EL4(r[0][j >> 2], j & 3), EL4(r[1][j >> 2], j & 3));
        p.y = pk2bf(EL4(r[2][j >> 2], j & 3), EL4(r[3][j >> 2], j & 3));
        *(uint2*)(xt + (cc * 16 + j) * 64 + q * 8) = p;
      }
      __syncthreads();                     // publish xt
      s8v oh0, oh1;
#pragma unroll
      for (int j = 0; j < 8; ++j) {
        const unsigned a = ((j < 4 ? awv.x >> (8 * j) : awv.y >> (8 * (j - 4)))) & 255u;
        oh0[j] = (a == (unsigned)l16) ? (short)0x3F80 : (short)0;
        oh1[j] = (a == (unsigned)(16 + l16)) ? (short)0x3F80 : (short)0;
      }
#pragma unroll
      for (int ct = 0; ct < 8; ++ct) {
        s8v af = *(const s8v*)(xt + (w * 128 + ct * 16 + l16) * 64 + g * 16);
        acc[ct][0] = __builtin_amdgcn_mfma_f32_16x16x32_bf16(af, oh0, acc[ct][0], 0, 0, 0);
        acc[ct][1] = __builtin_amdgcn_mfma_f32_16x16x32_bf16(af, oh1, acc[ct][1], 0, 0, 0);
      }
    }
    __syncthreads();                       // xt/saL reuse safe for next chunk
  }

  // ---- flush + counts (R11 verbatim; sa from LDS) ----
  const int pb = blockIdx.x & 7;
#pragma unroll
  for (int ct = 0; ct < 8; ++ct)
#pragma unroll
    for (int tc = 0; tc < 2; ++tc) {
      const int c = tc * 16 + l16;
      const int xcol = w * 128 + ct * 16 + 4 * g;
#pragma unroll
      for (int r = 0; r < 4; ++r)
        atomicAdd(&gsums[pb * 16384 + c * HH + xcol + r], acc[ct][tc][r]);
    }

  if (w == 0 && l < CC) {
    int cnt = 0;
    for (int i = 0; i < 512; i += 4) {
      const unsigned wd = *(const unsigned*)(saL + i);
      cnt += (int)((wd & 255u) == (unsigned)l) + (int)(((wd >> 8) & 255u) == (unsigned)l) +
             (int)(((wd >> 16) & 255u) == (unsigned)l) + (int)(((wd >> 24) & 255u) == (unsigned)l);
    }
    atomicAdd(&gcounts[pb * 32 + l], (float)cnt);
  }
}

// ---------------------------------------------------------------------------
// Kernel 3: reduce 8 partials + EMA centroid update — R8+ exact
// ---------------------------------------------------------------------------
__global__ void k_upd(const float* __restrict__ cent, const float* __restrict__ sums,
                      const float* __restrict__ counts, float* __restrict__ upd) {
  const int i = blockIdx.x * 256 + threadIdx.x;   // 16384
  const int c = i >> 9;
  float s = 0.f, cnt = 0.f;
#pragma unroll
  for (int b = 0; b < 8; ++b) { s += sums[b * 16384 + i]; cnt += counts[b * 32 + c]; }
  const float mean = s / fmaxf(cnt, 1.f);
  upd[i] = (cnt > 0.f) ? (MOMF * cent[i] + (1.f - MOMF) * mean) : cent[i];
}

// ---------------------------------------------------------------------------
// Kernel 4: k = upd@Wk + bk ; v = upd@Wv + bv   (32x512 each) — R2 exact
// ---------------------------------------------------------------------------
__global__ void k_kv(const float* __restrict__ upd,
                     const float* __restrict__ Wk, const float* __restrict__ bk,
                     const float* __restrict__ Wv, const float* __restrict__ bv,
                     float* __restrict__ kbuf, float* __restrict__ vbuf) {
  const int o = blockIdx.x * 256 + threadIdx.x;   // 0..32767
  const int sel = o >> 14;
  const int idx = o & 16383;
  const int c = idx >> 9, j = idx & 511;
  const float* W = sel ? Wv : Wk;
  const float* b = sel ? bv : bk;
  const float* u = upd + c * HH;
  float s = b[j];
  for (int i = 0; i < HH; ++i) s += u[i] * W[i * HH + j];
  (sel ? vbuf : kbuf)[idx] = s;
}

// ---------------------------------------------------------------------------
// Kernel 5: Mt/Pt slice-major — R12-R15 exact.
// ---------------------------------------------------------------------------
__global__ void k_msp(const float* __restrict__ Wq, const float* __restrict__ bq,
                      const float* __restrict__ kbuf, const float* __restrict__ vbuf,
                      const float* __restrict__ Wo, const float* __restrict__ bo,
                      unsigned short* __restrict__ Mt, float* __restrict__ sb,
                      unsigned short* __restrict__ Pt) {
  const int b = blockIdx.x, t = threadIdx.x;
  const float scale = 0.125f;   // 1/sqrt(64)
  if (b < 512) {
    const int o = b * 256 + t;          // hc*512 + i
    const int hc = o >> 9, i = o & 511;
    const int h = hc >> 5, c = hc & 31;
    const float* wq = Wq + i * HH + h * 64;
    const float* kr = kbuf + c * HH + h * 64;
    float s = 0.f;
#pragma unroll
    for (int d = 0; d < 64; ++d) s += wq[d] * kr[d];
    Mt[(i >> 5) * 8192 + hc * 32 + (i & 31)] = f2bf(s * scale);
  } else if (b < 1024) {
    const int o = b - 512;              // output col (0..511)
    const int hc = t;                   // 0..255
    const int h = hc >> 5, c = hc & 31;
    const float* vr = vbuf + c * HH + h * 64;
    const float* wo = Wo + h * 64 * HH + o;
    float s = 0.f;
#pragma unroll
    for (int d = 0; d < 64; ++d) s += vr[d] * wo[d * HH];
    Pt[h * 16384 + o * 32 + (hc & 31)] = f2bf(s + bo[o] * scale);
  } else if (t < 256) {
    const int h = t >> 5, c = t & 31;
    const float* kr = kbuf + c * HH + h * 64;
    const float* bqp = bq + h * 64;
    float s = 0.f;
#pragma unroll
    for (int d = 0; d < 64; ++d) s += bqp[d] * kr[d];
    sb[t] = s * scale;
  }
}

// ---------------------------------------------------------------------------
// Kernel 6 (main, MFMA): R15 exact (best measured: 517 µs) — single-barrier
// double-buffered pipeline, BM=64, 256 thr.
// ---------------------------------------------------------------------------
__global__ __launch_bounds__(256, 2) void k_main(
    const float* __restrict__ x, const unsigned short* __restrict__ Mt,
    const float* __restrict__ sb, const unsigned short* __restrict__ Pt,
    const float* __restrict__ lnw, const float* __restrict__ lnb,
    float* __restrict__ y) {
  __shared__ __align__(16) unsigned char smem[40960];  // dbuf 2x20480 / store win
  float* yb = (float*)smem;                            // [16][520] fp32 window
  const unsigned char* Mtb = (const unsigned char*)Mt;
  const unsigned char* Ptb = (const unsigned char*)Pt;
  const int tid = threadIdx.x;
  const int w = tid >> 6, l = tid & 63;
  const int l16 = l & 15, g = l >> 4;            // lane column / k-group
  const size_t n0 = (size_t)blockIdx.x * 64;
  const size_t xrow = n0 + w * 16 + l16;
  const float* xr = x + xrow * HH;

  // ---- phase 1 prologue: stage Mt slice 0 -> buf0; prefetch x(0) ----
  {
    const unsigned char* src = Mtb + tid * 64;
    u4v r0 = *(const u4v*)(src), r1 = *(const u4v*)(src + 16);
    u4v r2 = *(const u4v*)(src + 32), r3 = *(const u4v*)(src + 48);
    unsigned char* dst = smem + tid * 80;
    *(u4v*)(dst) = r0; *(u4v*)(dst + 16) = r1;
    *(u4v*)(dst + 32) = r2; *(u4v*)(dst + 48) = r3;
  }
  float4 xa_c = *(const float4*)&xr[g * 8];
  float4 xb_c = *(const float4*)&xr[g * 8 + 4];
  __syncthreads();

  f4v acc1[16];
#pragma unroll
  for (int tc = 0; tc < 16; ++tc)
    acc1[tc] = *(const f4v*)&sb[tc * 16 + 4 * g];

  // ---- phase 1: 16 steps, 1 barrier each ----
#pragma unroll
  for (int kk = 0; kk < 16; ++kk) {
    const int cur = (kk & 1) * 20480, nxt = ((kk + 1) & 1) * 20480;
    u4v r0, r1, r2, r3;
    float4 xa_n, xb_n;
    {
      const unsigned char* src =
          (kk < 15) ? (Mtb + (kk + 1) * 16384 + tid * 64) : (Ptb + tid * 64);
      r0 = *(const u4v*)(src); r1 = *(const u4v*)(src + 16);
      r2 = *(const u4v*)(src + 32); r3 = *(const u4v*)(src + 48);
    }
    if (kk < 15) {
      xa_n = *(const float4*)&xr[(kk + 1) * 32 + g * 8];
      xb_n = *(const float4*)&xr[(kk + 1) * 32 + g * 8 + 4];
    }
    s8v bfrag;
    bfrag[0] = (short)f2bf(xa_c.x); bfrag[1] = (short)f2bf(xa_c.y);
    bfrag[2] = (short)f2bf(xa_c.z); bfrag[3] = (short)f2bf(xa_c.w);
    bfrag[4] = (short)f2bf(xb_c.x); bfrag[5] = (short)f2bf(xb_c.y);
    bfrag[6] = (short)f2bf(xb_c.z); bfrag[7] = (short)f2bf(xb_c.w);
#pragma unroll
    for (int tc = 0; tc < 16; ++tc) {
      s8v afrag = *(const s8v*)(smem + cur + (tc * 16 + l16) * 80 + g * 16);
      acc1[tc] = __builtin_amdgcn_mfma_f32_16x16x32_bf16(afrag, bfrag, acc1[tc], 0, 0, 0);
    }
    {
      unsigned char* dst = smem + nxt + tid * 80;
      *(u4v*)(dst) = r0; *(u4v*)(dst + 16) = r1;
      *(u4v*)(dst + 32) = r2; *(u4v*)(dst + 48) = r3;
    }
    __syncthreads();
    if (kk < 15) { xa_c = xa_n; xb_c = xb_n; }
  }
  // buf0 now holds Pt half-slice 0 (published by the kk=15 barrier)

  // ---- softmax per head h (cols 32h..32h+31): 8 in-lane + xor16/xor32 ----
  unsigned int apk[16][2];
#pragma unroll
  for (int h = 0; h < 8; ++h) {
    f4v s0 = acc1[2 * h], s1 = acc1[2 * h + 1];
    float m = fmaxf(fmaxf(fmaxf(s0[0], s0[1]), fmaxf(s0[2], s0[3])),
                    fmaxf(fmaxf(s1[0], s1[1]), fmaxf(s1[2], s1[3])));
    m = fmaxf(m, __shfl_xor(m, 16));
    m = fmaxf(m, __shfl_xor(m, 32));
    float e0 = __expf(s0[0] - m), e1 = __expf(s0[1] - m);
    float e2 = __expf(s0[2] - m), e3 = __expf(s0[3] - m);
    float e4 = __expf(s1[0] - m), e5 = __expf(s1[1] - m);
    float e6 = __expf(s1[2] - m), e7 = __expf(s1[3] - m);
    float sum = ((e0 + e1) + (e2 + e3)) + ((e4 + e5) + (e6 + e7));
    sum += __shfl_xor(sum, 16);
    sum += __shfl_xor(sum, 32);
    const float inv = 1.f / sum;
    apk[2 * h][0] = pk2bf(e0 * inv, e1 * inv);
    apk[2 * h][1] = pk2bf(e2 * inv, e3 * inv);
    apk[2 * h + 1][0] = pk2bf(e4 * inv, e5 * inv);
    apk[2 * h + 1][1] = pk2bf(e6 * inv, e7 * inv);
  }

  // ---- phase 2: 16 half-slice steps (h = s>>1, col-half = s&1) ----
  f4v acc2[32];
#pragma unroll
  for (int to = 0; to < 32; ++to) acc2[to] = (f4v){0.f, 0.f, 0.f, 0.f};

#pragma unroll
  for (int s = 0; s < 16; ++s) {
    const int cur = (s & 1) * 20480, nxt = ((s + 1) & 1) * 20480;
    const int h = s >> 1, half = s & 1;
    u4v r0, r1, r2, r3;
    if (s < 15) {
      const unsigned char* src = Ptb + (s + 1) * 16384 + tid * 64;
      r0 = *(const u4v*)(src); r1 = *(const u4v*)(src + 16);
      r2 = *(const u4v*)(src + 32); r3 = *(const u4v*)(src + 48);
    }
    unsigned int dw[4];
#pragma unroll
    for (int d = 0; d < 4; ++d) {
      const int gsrc = 2 * (g & 1) + (d >> 1);
      const int src = l16 + 16 * gsrc;
      unsigned int t0 = (unsigned int)__shfl((int)apk[2 * h][d & 1], src, 64);
      unsigned int t1 = (unsigned int)__shfl((int)apk[2 * h + 1][d & 1], src, 64);
      dw[d] = (g < 2) ? t0 : t1;
    }
    u4v bu; bu[0] = dw[0]; bu[1] = dw[1]; bu[2] = dw[2]; bu[3] = dw[3];
    s8v bfrag = __builtin_bit_cast(s8v, bu);
#pragma unroll
    for (int tl = 0; tl < 16; ++tl) {
      s8v afrag = *(const s8v*)(smem + cur + (tl * 16 + l16) * 80 + g * 16);
      acc2[half * 16 + tl] =
          __builtin_amdgcn_mfma_f32_16x16x32_bf16(afrag, bfrag, acc2[half * 16 + tl], 0, 0, 0);
    }
    if (s < 15) {
      unsigned char* dst = smem + nxt + tid * 80;
      *(u4v*)(dst) = r0; *(u4v*)(dst + 16) = r1;
      *(u4v*)(dst + 32) = r2; *(u4v*)(dst + 48) = r3;
    }
    __syncthreads();
  }

  // ---- epilogue: +residual (bo folded into Pt), LN in registers ----
  float s1 = 0.f, s2 = 0.f;
#pragma unroll
  for (int to = 0; to < 32; ++to) {
    float4 xv = *(const float4*)&xr[to * 16 + 4 * g];
    acc2[to][0] += xv.x; acc2[to][1] += xv.y;
    acc2[to][2] += xv.z; acc2[to][3] += xv.w;
    s1 += (acc2[to][0] + acc2[to][1]) + (acc2[to][2] + acc2[to][3]);
    s2 += (acc2[to][0] * acc2[to][0] + acc2[to][1] * acc2[to][1]) +
          (acc2[to][2] * acc2[to][2] + acc2[to][3] * acc2[to][3]);
  }
  s1 += __shfl_xor(s1, 16); s2 += __shfl_xor(s2, 16);
  s1 += __shfl_xor(s1, 32); s2 += __shfl_xor(s2, 32);
  const float mean = s1 * (1.f / 512.f);
  const float var = s2 * (1.f / 512.f) - mean * mean;
  const float rstd = rsqrtf(var + 1e-5f);
#pragma unroll
  for (int to = 0; to < 32; ++to) {
    float4 wv = *(const float4*)&lnw[to * 16 + 4 * g];
    float4 bv = *(const float4*)&lnb[to * 16 + 4 * g];
    acc2[to][0] = (acc2[to][0] - mean) * rstd * wv.x + bv.x;
    acc2[to][1] = (acc2[to][1] - mean) * rstd * wv.y + bv.y;
    acc2[to][2] = (acc2[to][2] - mean) * rstd * wv.z + bv.z;
    acc2[to][3] = (acc2[to][3] - mean) * rstd * wv.w + bv.w;
  }

  // ---- store via LDS windows (R12 exact) ----
  const int prow = tid >> 7;               // 0..1
  const int pc = (tid & 127) * 4;          // float col within row
  for (int j = 0; j < 4; ++j) {
    __syncthreads();                       // window free / phase-2 reads done
    if (w == j) {
#pragma unroll
      for (int to = 0; to < 32; ++to)
        *(f4v*)&yb[l16 * 520 + to * 16 + 4 * g] = acc2[to];
    }
    __syncthreads();                       // publish
#pragma unroll
    for (int p = 0; p < 8; ++p)
      *(float4*)&y[(n0 + j * 16 + p * 2 + prow) * HH + pc] =
          *(const float4*)&yb[(p * 2 + prow) * 520 + pc];
  }
}

// ---------------------------------------------------------------------------
extern "C" void kernel_launch(void* const* d_in, const int* in_sizes, int n_in,
                              void* d_out, int out_size, void* d_ws, size_t ws_size,
                              hipStream_t stream) {
  const float* x    = (const float*)d_in[0];
  const float* cent = (const float*)d_in[1];
  const float* Wq   = (const float*)d_in[2];
  const float* bq   = (const float*)d_in[3];
  const float* Wk   = (const float*)d_in[4];
  const float* bk   = (const float*)d_in[5];
  const float* Wv   = (const float*)d_in[6];
  const float* bv   = (const float*)d_in[7];
  const float* Wo   = (const float*)d_in[8];
  const float* bo   = (const float*)d_in[9];
  const float* lnw  = (const float*)d_in[10];
  const float* lnb  = (const float*)d_in[11];
  float* ws = (float*)d_ws;
  float* y  = (float*)d_out;

  hipMemsetAsync(ws, 0, (8 * 16384 + 8 * 32) * sizeof(float), stream);
  k_km2<<<512, 256, 0, stream>>>(x, cent, ws + WS_SUMS, ws + WS_COUNTS);
  k_upd<<<64, 256, 0, stream>>>(cent, ws + WS_SUMS, ws + WS_COUNTS, ws + WS_UPD);
  k_kv<<<128, 256, 0, stream>>>(ws + WS_UPD, Wk, bk, Wv, bv,
                                ws + WS_KBUF, ws + WS_VBUF);
  k_msp<<<1025, 256, 0, stream>>>(Wq, bq, ws + WS_KBUF, ws + WS_VBUF, Wo, bo,
                                  (unsigned short*)(ws + WS_MT), ws + WS_SB,
                                  (unsigned short*)(ws + WS_PT));
  k_main<<<4096, 256, 0, stream>>>(x, (const unsigned short*)(ws + WS_MT),
                                   ws + WS_SB, (const unsigned short*)(ws + WS_PT),
                                   lnw, lnb, y);
}